// Round 1
// baseline (381.223 us; speedup 1.0000x reference)
//
#include <hip/hip_runtime.h>
#include <hip/hip_cooperative_groups.h>

namespace cg = cooperative_groups;

// Problem constants (from reference setup_inputs):
// b=16, c=64, l=8, h=56, w=56  ->  cl = 512, n = 56*56 = 3136
#define BATCH 16
#define CL    512
#define NSP   3136
#define N4    (NSP / 4)            // 784 float4 per (b,c) row
#define CHUNK 16                   // i4 positions per phase-1 slab
#define NCHUNK (N4 / CHUNK)        // 49 (exact: 784 = 49*16, no tail)
#define GROUPS 16                  // channel groups per block
#define CPG   (CL / GROUPS)        // 32 channels per group
#define NBLK  (BATCH * NCHUNK)     // 784 blocks (~3 blocks/CU on 256 CUs)

#define F4_TOTAL     (BATCH * CL * N4)      // 6422528
#define F4_PER_BLK   (F4_TOTAL / NBLK)      // 8192 (exact)
#define F4_PER_BATCH (CL * N4)              // 401408
#define BLK_PER_BATCH (F4_PER_BATCH / F4_PER_BLK)  // 49 (exact)

typedef float nfloat4 __attribute__((ext_vector_type(4)));

// ---------------------------------------------------------------------------
// Fused cooperative kernel:
//   Phase 1 : g[b,i] = sum_c x[b,c,i]*g_w[c]  (final, to ws)
//             t_slab[blk] = sum_{i in slab} sum_c x[b,c,i]*theta_w[c]
//   sync
//   Phase1.5: m[b] = (sum over 49 slabs) / NSP     (blocks 0..15)
//   sync
//   Phase 2 : out = x + m[b]*g[b,i]*h_w[c] + h_b[c]
//             (x re-read hits L3: 98 MiB < 256 MiB Infinity Cache)
// Block: 256 threads = 16 i4-lanes x 16 channel-groups.
// Grid:  784 blocks; __launch_bounds__(256,4) guarantees co-residency
//        (4 blocks/CU * 256 CUs = 1024 >= 784).
// ---------------------------------------------------------------------------
__global__ __launch_bounds__(256, 4) void sa_fused(
    const float* __restrict__ x,        // [BATCH, CL, NSP]
    const float* __restrict__ theta_w,  // [CL]
    const float* __restrict__ g_w,      // [CL]
    const float* __restrict__ h_w,      // [CL]
    const float* __restrict__ h_b,      // [CL]
    float* __restrict__ out,            // [BATCH, CL, NSP]
    float* __restrict__ g_ws,           // ws: [BATCH*N4] float4
    float* __restrict__ t_ws,           // ws: [NBLK] slab partials
    float* __restrict__ m_ws)           // ws: [BATCH]
{
    cg::grid_group grid = cg::this_grid();
    const int blk = blockIdx.x;
    const int tid = threadIdx.x;

    // ---------------- Phase 1 ----------------
    {
        const int b     = blk / NCHUNK;
        const int chunk = blk % NCHUNK;
        const int tx = tid & (CHUNK - 1);   // i4 lane 0..15
        const int gq = tid >> 4;            // channel group 0..15
        const int i4 = chunk * CHUNK + tx;  // always < 784 (exact tiling)

        const float4* xb = (const float4*)x + (size_t)b * CL * N4 + i4;

        float4 gv = make_float4(0.f, 0.f, 0.f, 0.f);
        float4 tv = make_float4(0.f, 0.f, 0.f, 0.f);
        const int c0 = gq * CPG;
        #pragma unroll 8
        for (int c = c0; c < c0 + CPG; ++c) {
            float4 xv = xb[(size_t)c * N4];   // 16 lanes x 16B contiguous
            const float gw = g_w[c];
            const float tw = theta_w[c];
            gv.x += xv.x * gw; gv.y += xv.y * gw;
            gv.z += xv.z * gw; gv.w += xv.w * gw;
            tv.x += xv.x * tw; tv.y += xv.y * tw;
            tv.z += xv.z * tw; tv.w += xv.w * tw;
        }

        __shared__ float4 sg[GROUPS][CHUNK];
        __shared__ float  st[GROUPS][CHUNK];
        sg[gq][tx] = gv;
        st[gq][tx] = tv.x + tv.y + tv.z + tv.w;
        __syncthreads();

        if (tid < CHUNK) {   // 16 threads finish the cross-group reduction
            float4 G = sg[0][tid];
            float  T = st[0][tid];
            #pragma unroll
            for (int k = 1; k < GROUPS; ++k) {
                float4 a = sg[k][tid];
                G.x += a.x; G.y += a.y; G.z += a.z; G.w += a.w;
                T += st[k][tid];
            }
            ((float4*)g_ws)[(size_t)b * N4 + chunk * CHUNK + tid] = G;

            #pragma unroll
            for (int off = CHUNK / 2; off > 0; off >>= 1)
                T += __shfl_down(T, off, CHUNK);
            if (tid == 0)
                t_ws[blk] = T;
        }
    }

    grid.sync();

    // ---------------- Phase 1.5: m[b] (blocks 0..15, wave 0) ----------------
    if (blk < BATCH && tid < 64) {
        float v = (tid < NCHUNK) ? t_ws[blk * NCHUNK + tid] : 0.f;
        #pragma unroll
        for (int off = 32; off > 0; off >>= 1)
            v += __shfl_down(v, off, 64);
        if (tid == 0)
            m_ws[blk] = v * (1.0f / (float)NSP);
    }

    grid.sync();

    // ---------------- Phase 2 ----------------
    {
        const int b2 = blk / BLK_PER_BATCH;         // each block stays in one b
        const float m = m_ws[b2];
        const float4* gb = (const float4*)g_ws + (size_t)b2 * N4;
        const size_t base = (size_t)blk * F4_PER_BLK + tid;
        const int local0 = (blk % BLK_PER_BATCH) * F4_PER_BLK + tid;

        #pragma unroll 4
        for (int r = 0; r < F4_PER_BLK / 256; ++r) {   // 32 iterations
            const size_t f  = base + (size_t)r * 256;  // global float4 index
            const int local = local0 + r * 256;        // within-batch index
            const int c  = local / N4;                 // magic-mul division
            const int ip = local - c * N4;

            float4 xv  = ((const float4*)x)[f];        // L3 hit (warmed phase 1)
            float4 gvv = gb[ip];                       // L2-hot (12.5 KB/batch)
            const float hb = h_b[c];
            const float mh = m * h_w[c];

            nfloat4 o;
            o.x = xv.x + mh * gvv.x + hb;
            o.y = xv.y + mh * gvv.y + hb;
            o.z = xv.z + mh * gvv.z + hb;
            o.w = xv.w + mh * gvv.w + hb;
            // Nontemporal: out is never re-read; don't evict x from L2/L3.
            __builtin_nontemporal_store(o, (nfloat4*)out + f);
        }
    }
}

extern "C" void kernel_launch(void* const* d_in, const int* in_sizes, int n_in,
                              void* d_out, int out_size, void* d_ws, size_t ws_size,
                              hipStream_t stream)
{
    const float* x       = (const float*)d_in[0];
    const float* theta_w = (const float*)d_in[1];
    const float* g_w     = (const float*)d_in[2];
    const float* h_w     = (const float*)d_in[3];
    const float* h_b     = (const float*)d_in[4];
    float* out = (float*)d_out;

    // Workspace layout (all fully written before read; no memset needed):
    //   [0, 200704)           : g_ws  (BATCH*N4 float4)
    //   [200704, 203840)      : t_ws  (NBLK floats = 3136 B, padded)
    //   [204800, 204864)      : m_ws  (BATCH floats)
    float* g_ws = (float*)d_ws;
    float* t_ws = (float*)((char*)d_ws + (size_t)BATCH * N4 * 16);
    float* m_ws = (float*)((char*)d_ws + (size_t)BATCH * N4 * 16 + 4096);

    void* args[] = { (void*)&x, (void*)&theta_w, (void*)&g_w, (void*)&h_w,
                     (void*)&h_b, (void*)&out, (void*)&g_ws, (void*)&t_ws,
                     (void*)&m_ws };
    hipLaunchCooperativeKernel((const void*)sa_fused, dim3(NBLK), dim3(256),
                               args, 0, stream);
}

// Round 2
// 202.227 us; speedup vs baseline: 1.8851x; 1.8851x over previous
//
#include <hip/hip_runtime.h>

// Problem constants (from reference setup_inputs):
// b=16, c=64, l=8, h=56, w=56  ->  cl = 512, n = 56*56 = 3136
#define BATCH 16
#define CL    512
#define NSP   3136
#define N4    (NSP / 4)            // 784 float4 per (b,c) row

// ---- pass 1 geometry: channel-split for occupancy ----
#define CSPLIT 8                   // c-slices per (b, i-chunk)
#define CPB    (CL / CSPLIT)       // 64 channels per block
#define CPT    (CPB / 4)           // 16 channels per thread (4 waves/block)
#define I4PB   64                  // i4 positions per block (one wave-width)
#define ICH    ((N4 + I4PB - 1) / I4PB)   // 13 i-chunks (last partial)
#define TP_PER_B (CSPLIT * ICH)    // 104 t-partials per batch

// ---- pass 2 geometry (unchanged from 200us baseline, minus t-reduce) ----
#define P2_F4_PER_BLOCK 512
#define F4_PER_BATCH (CL * N4)     // 401408
#define P2_BLOCKS ((BATCH * F4_PER_BATCH) / P2_F4_PER_BLOCK)   // 12544

typedef float nfloat4 __attribute__((ext_vector_type(4)));

// ---------------------------------------------------------------------------
// Pass 1: partial projections.
//   g_part[s][b][i4] = sum_{c in slice s} x[b,c,i4]*g_w[c]   (float4)
//   t_part[b][s*ICH+ichunk] = sum over block's (i,c) of x*theta_w
// Grid: (13, 8, 16) = 1664 blocks (~6.5/CU, ~26 waves/CU).
// Block: 256 = 64 i4-lanes (wave-coalesced 1KiB/load) x 4 c-subranges.
// ---------------------------------------------------------------------------
__global__ __launch_bounds__(256) void sa_pass1(
    const float* __restrict__ x,        // [BATCH, CL, NSP]
    const float* __restrict__ theta_w,  // [CL]
    const float* __restrict__ g_w,      // [CL]
    float* __restrict__ g_part,         // ws: [CSPLIT][BATCH][N4] float4
    float* __restrict__ t_part)         // ws: [BATCH][TP_PER_B]
{
    const int ichunk = blockIdx.x;       // 0..12
    const int s      = blockIdx.y;       // 0..7
    const int b      = blockIdx.z;       // 0..15
    const int tid    = threadIdx.x;
    const int lane   = tid & 63;
    const int wq     = tid >> 6;         // c-subrange within slice, 0..3
    const int i4     = ichunk * I4PB + lane;
    const bool valid = (i4 < N4);
    const int c0     = s * CPB + wq * CPT;

    const float4* xb = (const float4*)x + ((size_t)b * CL + c0) * N4 + i4;

    float4 gv = make_float4(0.f, 0.f, 0.f, 0.f);
    float4 tv = make_float4(0.f, 0.f, 0.f, 0.f);
    if (valid) {
        #pragma unroll
        for (int k = 0; k < CPT; ++k) {      // 16 independent 1KiB wave-loads
            float4 xv = xb[(size_t)k * N4];
            const float gw = g_w[c0 + k];    // wave-uniform -> s_load
            const float tw = theta_w[c0 + k];
            gv.x += xv.x * gw; gv.y += xv.y * gw;
            gv.z += xv.z * gw; gv.w += xv.w * gw;
            tv.x += xv.x * tw; tv.y += xv.y * tw;
            tv.z += xv.z * tw; tv.w += xv.w * tw;
        }
    }

    __shared__ float4 sg[4][I4PB];
    __shared__ float  st[4][I4PB];
    sg[wq][lane] = gv;
    st[wq][lane] = tv.x + tv.y + tv.z + tv.w;   // invalid lanes wrote zeros
    __syncthreads();

    if (tid < I4PB) {   // wave 0 finishes the 4-way cross-wave reduction
        float4 G = sg[0][tid];
        float  T = st[0][tid];
        #pragma unroll
        for (int k = 1; k < 4; ++k) {
            float4 a = sg[k][tid];
            G.x += a.x; G.y += a.y; G.z += a.z; G.w += a.w;
            T += st[k][tid];
        }
        if (valid)
            ((float4*)g_part)[((size_t)s * BATCH + b) * N4 + i4] = G;

        #pragma unroll
        for (int off = 32; off > 0; off >>= 1)
            T += __shfl_down(T, off, 64);
        if (tid == 0)
            t_part[b * TP_PER_B + s * ICH + ichunk] = T;
    }
}

// ---------------------------------------------------------------------------
// Combine: g[b,i4] = sum_s g_part[s][b,i4];  m[b] = (sum t_part[b,:]) / NSP
// Grid: 50 blocks. Blocks 0..48 combine g (49*256 = 12544 = BATCH*N4 exact);
// block 49 computes all 16 m values (16 lanes per batch).
// Reads 1.6MB (L2-hot), writes 196KB. ~3us.
// ---------------------------------------------------------------------------
__global__ __launch_bounds__(256) void sa_combine(
    const float* __restrict__ g_part,   // [CSPLIT][BATCH][N4] float4
    const float* __restrict__ t_part,   // [BATCH][TP_PER_B]
    float* __restrict__ g_out,          // [BATCH][N4] float4
    float* __restrict__ m_out)          // [BATCH]
{
    const int blk = blockIdx.x;
    const int tid = threadIdx.x;

    if (blk < 49) {
        const int idx = blk * 256 + tid;           // 0..12543 = b*N4 + i4
        float4 G = make_float4(0.f, 0.f, 0.f, 0.f);
        #pragma unroll
        for (int s = 0; s < CSPLIT; ++s) {
            float4 a = ((const float4*)g_part)[(size_t)s * BATCH * N4 + idx];
            G.x += a.x; G.y += a.y; G.z += a.z; G.w += a.w;
        }
        ((float4*)g_out)[idx] = G;
    } else {
        // 16 lanes per batch sum the 104 t-partials.
        const int b  = tid >> 4;      // 0..15
        const int l16 = tid & 15;
        float T = 0.f;
        for (int k = l16; k < TP_PER_B; k += 16)
            T += t_part[b * TP_PER_B + k];
        #pragma unroll
        for (int off = 8; off > 0; off >>= 1)
            T += __shfl_down(T, off, 16);
        if (l16 == 0)
            m_out[b] = T * (1.0f / (float)NSP);
    }
}

// ---------------------------------------------------------------------------
// Pass 2: out[b,c,i] = x[b,c,i] + m[b]*g[b,i]*h_w[c] + h_b[c]
// Block covers 512 consecutive float4 (2/thread); 401408 % 512 == 0 so each
// block sees one batch. Grid 12544 blocks (8 blocks/CU -> 32 waves/CU).
// x re-read hits L3 (98MiB, warmed by pass1). Nontemporal store of out.
// ---------------------------------------------------------------------------
__global__ __launch_bounds__(256) void sa_pass2(
    const float* __restrict__ x,
    const float* __restrict__ g_arr,   // [BATCH][N4] float4
    const float* __restrict__ m_arr,   // [BATCH]
    const float* __restrict__ h_w,     // [CL]
    const float* __restrict__ h_b,     // [CL]
    float* __restrict__ out)
{
    const int blk = blockIdx.x;
    const int b   = blk / (F4_PER_BATCH / P2_F4_PER_BLOCK);   // blk/784
    const float m = m_arr[b];                                  // uniform s_load

    const size_t base = (size_t)blk * P2_F4_PER_BLOCK + threadIdx.x;
    #pragma unroll
    for (int r = 0; r < P2_F4_PER_BLOCK / 256; ++r) {
        const size_t f = base + (size_t)r * 256;     // global float4 index
        const int i4 = (int)(f % N4);                // magic-mul, no div unit
        const int bc = (int)(f / N4);
        const int c  = bc & (CL - 1);

        float4 xv = ((const float4*)x)[f];
        float4 gv = ((const float4*)g_arr)[(size_t)b * N4 + i4];
        const float hb = h_b[c];
        const float mh = m * h_w[c];

        nfloat4 o;
        o.x = xv.x + mh * gv.x + hb;
        o.y = xv.y + mh * gv.y + hb;
        o.z = xv.z + mh * gv.z + hb;
        o.w = xv.w + mh * gv.w + hb;
        // Nontemporal: out is never re-read; keep x resident in L2/L3.
        __builtin_nontemporal_store(o, (nfloat4*)out + f);
    }
}

extern "C" void kernel_launch(void* const* d_in, const int* in_sizes, int n_in,
                              void* d_out, int out_size, void* d_ws, size_t ws_size,
                              hipStream_t stream)
{
    const float* x       = (const float*)d_in[0];
    const float* theta_w = (const float*)d_in[1];
    const float* g_w     = (const float*)d_in[2];
    const float* h_w     = (const float*)d_in[3];
    const float* h_b     = (const float*)d_in[4];
    float* out = (float*)d_out;

    // Workspace layout (every byte written before read; no memset needed):
    //   [0,        1605632) : g_part  (8*16*784 float4 = 1.53 MiB)
    //   [1605632,  1806336) : g_ws    (16*784 float4 = 196 KiB)
    //   [1806336,  1812992) : t_part  (1664 floats)
    //   [1814528,  1814592) : m_ws    (16 floats)
    char* ws = (char*)d_ws;
    float* g_part = (float*)ws;
    float* g_ws   = (float*)(ws + 1605632);
    float* t_ws   = (float*)(ws + 1806336);
    float* m_ws   = (float*)(ws + 1814528);

    dim3 grid1(ICH, CSPLIT, BATCH);   // (13, 8, 16) = 1664 blocks
    sa_pass1<<<grid1, 256, 0, stream>>>(x, theta_w, g_w, g_part, t_ws);

    sa_combine<<<50, 256, 0, stream>>>(g_part, t_ws, g_ws, m_ws);

    sa_pass2<<<P2_BLOCKS, 256, 0, stream>>>(x, g_ws, m_ws, h_w, h_b, out);
}